// Round 10
// baseline (177.804 us; speedup 1.0000x reference)
//
#include <hip/hip_runtime.h>

constexpr int BATCH = 8;
constexpr int CH    = 128;
constexpr int NPix  = 3072;          // 48*64
constexpr int NT    = 48;            // 64-pixel tiles per image
constexpr int NCHUNK = 4;            // split-m factor
constexpr int TPC   = NT / NCHUNK;   // tiles per chunk = 12
constexpr int MPC   = TPC * 64;      // m-values per chunk = 768
constexpr int TILE_SHORTS = 64 * CH; // 8192 bf16 per tile (16 KB)
constexpr float INV_SQRT_C = 0.08838834764831845f;

typedef __bf16 bf16x8 __attribute__((ext_vector_type(8)));
typedef float  floatx4 __attribute__((ext_vector_type(4)));

static __device__ __forceinline__ unsigned short f2bf(float f) {
  unsigned int u = __float_as_uint(f);
  u += 0x7fff + ((u >> 16) & 1);   // RNE
  return (unsigned short)(u >> 16);
}

// Load a [CH][64] fp32 tile (ch-major) into LDS T[CH][65] from [B][CH][NPix].
// Scalar LDS stores (stride-65 rows are NOT 16B-aligned — R4 bug).
static __device__ __forceinline__ void loadT(float (*T)[65],
                                             const float* __restrict__ src, int t) {
  const int cc = 4 * (t & 15);
  const int kb = t >> 4;
#pragma unroll
  for (int p = 0; p < 8; ++p) {
    const int k = kb + 16 * p;
    const float4 v = *(const float4*)(src + (size_t)k * NPix + cc);
    T[k][cc] = v.x; T[k][cc + 1] = v.y; T[k][cc + 2] = v.z; T[k][cc + 3] = v.w;
  }
}

// Write a 64x128 bf16 tile in MFMA fragment order.  (R6-proven.)
static __device__ __forceinline__ void writeFrag(unsigned short* __restrict__ dst,
                                                 const float (*T)[65], int t) {
#pragma unroll
  for (int i = 0; i < 4; ++i) {
    const int oi   = i * 256 + t;
    const int lane = oi & 63;
    const int kc   = (oi >> 6) & 3;
    const int c    = oi >> 8;
    const int r    = c * 16 + (lane & 15);
    const int ch0  = kc * 32 + (lane >> 4) * 8;
    unsigned short v[8];
#pragma unroll
    for (int j = 0; j < 8; ++j) v[j] = f2bf(T[ch0 + j][r]);
    *(uint4*)(dst + (size_t)oi * 8) = *(uint4*)v;
  }
}

// Stage one 16 KB fragment tile global -> LDS (256 thr x 4 uint4).
static __device__ __forceinline__ void stageK(unsigned short* __restrict__ dst,
                                              const unsigned short* __restrict__ src,
                                              int t) {
#pragma unroll
  for (int i = 0; i < 4; ++i)
    *(uint4*)&dst[(i * 256 + t) * 8] = *(const uint4*)(src + (size_t)(i * 256 + t) * 8);
}

// ---------------------------------------------------------------------------
// W2 = kw @ qw, b2 = kw @ qb + kb.  (R6-proven, verbatim.)
// ---------------------------------------------------------------------------
__global__ __launch_bounds__(256) void w2_kernel(
    const float* __restrict__ qw, const float* __restrict__ qb,
    const float* __restrict__ kw, const float* __restrict__ kb,
    float* __restrict__ W2, float* __restrict__ b2) {
  const int t = threadIdx.x;
  const int o = blockIdx.x * 2 + (t >> 7);
  const int i = t & 127;
  float acc = 0.f;
#pragma unroll 8
  for (int j = 0; j < CH; ++j)
    acc = fmaf(kw[o * CH + j], qw[j * CH + i], acc);
  W2[o * CH + i] = acc;
  if (i == 0) {
    float a2 = kb[o];
#pragma unroll 8
    for (int j = 0; j < CH; ++j) a2 = fmaf(kw[o * CH + j], qb[j], a2);
    b2[o] = a2;
  }
}

// ---------------------------------------------------------------------------
// f1 -> f1t only (384 blocks).
// ---------------------------------------------------------------------------
__global__ __launch_bounds__(256, 2) void cvt_kernel(
    const float* __restrict__ f1, unsigned short* __restrict__ f1t) {
  __shared__ float T[CH][65];
  const int t = threadIdx.x;
  const int b = blockIdx.x / NT, tile = blockIdx.x % NT;
  loadT(T, f1 + (size_t)b * CH * NPix + tile * 64, t);
  __syncthreads();
  writeFrag(f1t + (size_t)blockIdx.x * TILE_SHORTS, T, t);
}

// ---------------------------------------------------------------------------
// fp32 VALU projection, ONE mat per block (768 blocks).  Inner loops are R6
// verbatim -> q/k values bit-identical to the 0.125-proven R6 path.
// mat==0 blocks (q) also emit f0t from the already-staged tile.
// ---------------------------------------------------------------------------
__global__ __launch_bounds__(256, 2) void proj_kernel(
    const float* __restrict__ f0, const float* __restrict__ qw,
    const float* __restrict__ qb, const float* __restrict__ W2,
    const float* __restrict__ b2, unsigned short* __restrict__ f0t,
    unsigned short* __restrict__ qt, unsigned short* __restrict__ kt) {
  __shared__ float T[CH][65];
  const int t = threadIdx.x;
  const int mat = blockIdx.x / (BATCH * NT);
  const int bi  = blockIdx.x % (BATCH * NT);
  const int b = bi / NT, tile = bi % NT;
  const size_t tb = (size_t)bi * TILE_SHORTS;

  loadT(T, f0 + (size_t)b * CH * NPix + tile * 64, t);
  __syncthreads();
  if (mat == 0) writeFrag(f0t + tb, T, t);

  const float* wgt  = mat ? W2 : qw;
  const float* bias = mat ? b2 : qb;
  unsigned short* dst = mat ? kt : qt;

  const int tn = t & 7, tm = t >> 3;
  const int co0 = 4 * tm, nn0 = 8 * tn;
  const int kcf = co0 >> 5, quadf = (co0 >> 3) & 3, jo = co0 & 7;

  float aq[4][8];
#pragma unroll
  for (int i = 0; i < 4; ++i)
#pragma unroll
    for (int j = 0; j < 8; ++j) aq[i][j] = 0.f;

  for (int k0 = 0; k0 < CH; k0 += 4) {
    float wv[4][4];
#pragma unroll
    for (int i = 0; i < 4; ++i)
      *(float4*)&wv[i][0] = *(const float4*)(wgt + (co0 + i) * CH + k0);
#pragma unroll
    for (int kk = 0; kk < 4; ++kk) {
      float a[8];
      *(float4*)&a[0] = *(const float4*)&T[k0 + kk][nn0];
      *(float4*)&a[4] = *(const float4*)&T[k0 + kk][nn0 + 4];
#pragma unroll
      for (int i = 0; i < 4; ++i)
#pragma unroll
        for (int j = 0; j < 8; ++j) aq[i][j] = fmaf(wv[i][kk], a[j], aq[i][j]);
    }
  }
#pragma unroll
  for (int i = 0; i < 4; ++i) {
    const float bv = bias[co0 + i];
#pragma unroll
    for (int j = 0; j < 8; ++j) aq[i][j] += bv;
  }

#pragma unroll
  for (int jj = 0; jj < 8; ++jj) {
    const int r = nn0 + jj, c = r >> 4, lrow = r & 15;
    const size_t off =
        tb + ((size_t)((c * 4 + kcf) * 64 + quadf * 16 + lrow)) * 8 + jo;
    uint2 pq;
    pq.x = (unsigned int)f2bf(aq[0][jj]) | ((unsigned int)f2bf(aq[1][jj]) << 16);
    pq.y = (unsigned int)f2bf(aq[2][jj]) | ((unsigned int)f2bf(aq[3][jj]) << 16);
    *(uint2*)(dst + off) = pq;
  }
}

// ---------------------------------------------------------------------------
// Tile-paired, double-buffered flash corr.  (R9 verbatim, twice-green.)
// ---------------------------------------------------------------------------
__global__ __launch_bounds__(256, 3) void corr_part_kernel(
    const unsigned short* __restrict__ f0t, const unsigned short* __restrict__ f1t,
    float* __restrict__ P) {
  __shared__ unsigned short Ks[2][TILE_SHORTS];
  const int t = threadIdx.x;
  const int b = blockIdx.x / ((NT / 2) * NCHUNK);
  const int rem = blockIdx.x % ((NT / 2) * NCHUNK);
  const int tp = rem >> 2, chunk = rem & 3;
  const int lane = t & 63, wave = t >> 6, quad = lane >> 4, lrow = lane & 15;

  bf16x8 af[2][4];
#pragma unroll
  for (int s = 0; s < 2; ++s) {
    const unsigned short* qp = f0t + (size_t)(b * NT + 2 * tp + s) * TILE_SHORTS;
#pragma unroll
    for (int kc = 0; kc < 4; ++kc)
      af[s][kc] = *(const bf16x8*)(qp + ((wave * 4 + kc) * 64 + lane) * 8);
  }

  float l[2][4] = {{0}}, sx[2][4] = {{0}}, sy[2][4] = {{0}};

  stageK(Ks[0], f1t + (size_t)(b * NT + chunk * TPC) * TILE_SHORTS, t);

  for (int mi = 0; mi < TPC; ++mi) {
    const int mt = chunk * TPC + mi;
    __syncthreads();
    if (mi + 1 < TPC)
      stageK(Ks[(mi + 1) & 1],
             f1t + (size_t)(b * NT + mt + 1) * TILE_SHORTS, t);
    const unsigned short* KB = Ks[mi & 1];

    float ts[2][4] = {{0}};
#pragma unroll
    for (int c = 0; c < 4; ++c) {
      const float x = (float)(c * 16 + lrow);
#pragma unroll
      for (int s = 0; s < 2; ++s) {
        floatx4 acc = {0.f, 0.f, 0.f, 0.f};
#pragma unroll
        for (int kc = 0; kc < 4; ++kc) {
          const bf16x8 bf = *(const bf16x8*)&KB[((c * 4 + kc) * 64 + lane) * 8];
          acc = __builtin_amdgcn_mfma_f32_16x16x32_bf16(af[s][kc], bf, acc, 0, 0, 0);
        }
#pragma unroll
        for (int r = 0; r < 4; ++r) {
          const float e = __expf(acc[r] * INV_SQRT_C);
          ts[s][r] += e;
          sx[s][r] = fmaf(e, x, sx[s][r]);
        }
      }
    }
    const float y = (float)mt;
#pragma unroll
    for (int s = 0; s < 2; ++s)
#pragma unroll
      for (int r = 0; r < 4; ++r) {
        l[s][r] += ts[s][r];
        sy[s][r] = fmaf(y, ts[s][r], sy[s][r]);
      }
  }

#pragma unroll
  for (int off = 1; off < 16; off <<= 1)
#pragma unroll
    for (int s = 0; s < 2; ++s)
#pragma unroll
      for (int r = 0; r < 4; ++r) {
        l[s][r] += __shfl_xor(l[s][r], off);
        sx[s][r] += __shfl_xor(sx[s][r], off);
        sy[s][r] += __shfl_xor(sy[s][r], off);
      }
  if (lrow == 0) {
#pragma unroll
    for (int s = 0; s < 2; ++s)
#pragma unroll
      for (int r = 0; r < 4; ++r) {
        const int g = (b * NT + 2 * tp + s) * 64 + wave * 16 + quad * 4 + r;
        P[(g * 3 + 0) * 4 + chunk] = l[s][r];
        P[(g * 3 + 1) * 4 + chunk] = sx[s][r];
        P[(g * 3 + 2) * 4 + chunk] = sy[s][r];
      }
  }
}

// ---------------------------------------------------------------------------
// Tile-paired, double-buffered fused attn.  (R9 verbatim, twice-green.)
// ---------------------------------------------------------------------------
__global__ __launch_bounds__(256, 3) void attn_part_kernel(
    const unsigned short* __restrict__ qt, const unsigned short* __restrict__ kt,
    const float* __restrict__ P, float* __restrict__ flow_pred,
    float* __restrict__ P2) {
  __shared__ unsigned short Ks[2][TILE_SHORTS];
  __shared__ float FP[MPC][2];
  const int t = threadIdx.x;
  const int b = blockIdx.x / ((NT / 2) * NCHUNK);
  const int rem = blockIdx.x % ((NT / 2) * NCHUNK);
  const int tp = rem >> 2, chunk = rem & 3;
  const int lane = t & 63, wave = t >> 6, quad = lane >> 4, lrow = lane & 15;

  for (int rr = t; rr < MPC; rr += 256) {
    const int n = chunk * MPC + rr;
    const int g = b * NPix + n;
    const float4 lv = *(const float4*)&P[(g * 3 + 0) * 4];
    const float4 xv = *(const float4*)&P[(g * 3 + 1) * 4];
    const float4 yv = *(const float4*)&P[(g * 3 + 2) * 4];
    const float lsum = (lv.x + lv.y) + (lv.z + lv.w);
    const float inv = 1.f / lsum;
    FP[rr][0] = ((xv.x + xv.y) + (xv.z + xv.w)) * inv - (float)(n & 63);
    FP[rr][1] = ((yv.x + yv.y) + (yv.z + yv.w)) * inv - (float)(n >> 6);
  }

  if (tp == 0) {
    __syncthreads();   // FP ready before the global write
    for (int rr = t; rr < MPC; rr += 256) {
      const int n = chunk * MPC + rr;
      flow_pred[(size_t)(b * 2 + 0) * NPix + n] = FP[rr][0];
      flow_pred[(size_t)(b * 2 + 1) * NPix + n] = FP[rr][1];
    }
  }

  bf16x8 af[2][4];
#pragma unroll
  for (int s = 0; s < 2; ++s) {
    const unsigned short* qp = qt + (size_t)(b * NT + 2 * tp + s) * TILE_SHORTS;
#pragma unroll
    for (int kc = 0; kc < 4; ++kc)
      af[s][kc] = *(const bf16x8*)(qp + ((wave * 4 + kc) * 64 + lane) * 8);
  }

  float l[2][4] = {{0}}, sx[2][4] = {{0}}, sy[2][4] = {{0}};

  stageK(Ks[0], kt + (size_t)(b * NT + chunk * TPC) * TILE_SHORTS, t);

  for (int mi = 0; mi < TPC; ++mi) {
    const int mt = chunk * TPC + mi;
    __syncthreads();   // Ks[cur] staged + FP ready + prior reads done
    if (mi + 1 < TPC)
      stageK(Ks[(mi + 1) & 1],
             kt + (size_t)(b * NT + mt + 1) * TILE_SHORTS, t);
    const unsigned short* KB = Ks[mi & 1];

#pragma unroll
    for (int c = 0; c < 4; ++c) {
      const int mloc = mi * 64 + c * 16 + lrow;
      const float vx = FP[mloc][0], vy = FP[mloc][1];
#pragma unroll
      for (int s = 0; s < 2; ++s) {
        floatx4 acc = {0.f, 0.f, 0.f, 0.f};
#pragma unroll
        for (int kc = 0; kc < 4; ++kc) {
          const bf16x8 bf = *(const bf16x8*)&KB[((c * 4 + kc) * 64 + lane) * 8];
          acc = __builtin_amdgcn_mfma_f32_16x16x32_bf16(af[s][kc], bf, acc, 0, 0, 0);
        }
#pragma unroll
        for (int r = 0; r < 4; ++r) {
          const float e = __expf(acc[r] * INV_SQRT_C);
          l[s][r] += e;
          sx[s][r] = fmaf(e, vx, sx[s][r]);
          sy[s][r] = fmaf(e, vy, sy[s][r]);
        }
      }
    }
  }

#pragma unroll
  for (int off = 1; off < 16; off <<= 1)
#pragma unroll
    for (int s = 0; s < 2; ++s)
#pragma unroll
      for (int r = 0; r < 4; ++r) {
        l[s][r] += __shfl_xor(l[s][r], off);
        sx[s][r] += __shfl_xor(sx[s][r], off);
        sy[s][r] += __shfl_xor(sy[s][r], off);
      }
  if (lrow == 0) {
#pragma unroll
    for (int s = 0; s < 2; ++s)
#pragma unroll
      for (int r = 0; r < 4; ++r) {
        const int g = (b * NT + 2 * tp + s) * 64 + wave * 16 + quad * 4 + r;
        P2[(g * 3 + 0) * 4 + chunk] = l[s][r];
        P2[(g * 3 + 1) * 4 + chunk] = sx[s][r];
        P2[(g * 3 + 2) * 4 + chunk] = sy[s][r];
      }
  }
}

__global__ __launch_bounds__(256) void reduce_attn_kernel(
    const float* __restrict__ P2, float* __restrict__ flow) {
  const int g = blockIdx.x * 256 + threadIdx.x;  // 0..24575
  const float4 lv = *(const float4*)&P2[(g * 3 + 0) * 4];
  const float4 xv = *(const float4*)&P2[(g * 3 + 1) * 4];
  const float4 yv = *(const float4*)&P2[(g * 3 + 2) * 4];
  const float l = (lv.x + lv.y) + (lv.z + lv.w);
  const float inv = 1.f / l;
  const int b = g / NPix, n = g % NPix;
  flow[(size_t)(b * 2 + 0) * NPix + n] = ((xv.x + xv.y) + (xv.z + xv.w)) * inv;
  flow[(size_t)(b * 2 + 1) * NPix + n] = ((yv.x + yv.y) + (yv.z + yv.w)) * inv;
}

// ---------------------------------------------------------------------------
extern "C" void kernel_launch(void* const* d_in, const int* in_sizes, int n_in,
                              void* d_out, int out_size, void* d_ws,
                              size_t ws_size, hipStream_t stream) {
  const float* f0  = (const float*)d_in[0];
  const float* f1  = (const float*)d_in[1];
  const float* q_w = (const float*)d_in[2];
  const float* q_b = (const float*)d_in[3];
  const float* k_w = (const float*)d_in[4];
  const float* k_b = (const float*)d_in[5];

  float* out       = (float*)d_out;
  float* flow      = out;                              // output 0
  float* flow_pred = out + (size_t)BATCH * 2 * NPix;   // output 1

  const size_t tile_elems = (size_t)BATCH * NT * TILE_SHORTS;
  unsigned short* f0t = (unsigned short*)d_ws;
  unsigned short* f1t = f0t + tile_elems;
  unsigned short* qt  = f1t + tile_elems;
  unsigned short* kt  = qt + tile_elems;
  float* W2 = (float*)(kt + tile_elems);
  float* b2 = W2 + CH * CH;
  float* P  = b2 + CH;                       // 24576*12 floats
  float* P2 = P + (size_t)BATCH * NPix * 12;

  w2_kernel<<<64, 256, 0, stream>>>(q_w, q_b, k_w, k_b, W2, b2);
  cvt_kernel<<<BATCH * NT, 256, 0, stream>>>(f1, f1t);
  proj_kernel<<<2 * BATCH * NT, 256, 0, stream>>>(f0, q_w, q_b, W2, b2,
                                                  f0t, qt, kt);
  corr_part_kernel<<<BATCH * (NT / 2) * NCHUNK, 256, 0, stream>>>(f0t, f1t, P);
  attn_part_kernel<<<BATCH * (NT / 2) * NCHUNK, 256, 0, stream>>>(qt, kt, P,
                                                                  flow_pred, P2);
  reduce_attn_kernel<<<96, 256, 0, stream>>>(P2, flow);
}